// Round 8
// baseline (938.726 us; speedup 1.0000x reference)
//
#include <hip/hip_runtime.h>
#include <stdint.h>

#define NROWS 50000
#define KNB 16
#define DD 128
#define LN_EPS 1e-5f

typedef unsigned short ushort_t;

static __device__ __forceinline__ float bf2f(uint32_t u) {
    union { uint32_t i; float f; } v; v.i = u << 16; return v.f;
}
static __device__ __forceinline__ ushort_t f2bf(float f) {
    union { float f; uint32_t i; } v; v.f = f;
    uint32_t x = v.i;
    return (ushort_t)((x + 0x7fffu + ((x >> 16) & 1u)) >> 16);
}
static __device__ __forceinline__ uint32_t packbf(float a, float b) {
    return (uint32_t)f2bf(a) | ((uint32_t)f2bf(b) << 16);
}
static __device__ __forceinline__ float leaky(float v) {
    return v > 0.0f ? v : 0.01f * v;
}
// tanh(z) = 1 - 2/(e^{2z}+1); saturates correctly for |z| large (exp->inf/0)
static __device__ __forceinline__ float tanh_fast(float z) {
    float e = __expf(2.0f * z);
    return 1.0f - 2.0f / (e + 1.0f);
}

// Both 128x128 linears in ONE launch: blocks [0,halfGrid) do A (e_h), rest do B (e_t).
// out[r][j] = sum_d in[r][d]*W[j][d] + bias[j]; fp32 in/out, W staged LDS bf16.
// 256 threads: j = tid&127, half = tid>>7 handles 4 of the chunk's 8 rows.
__global__ __launch_bounds__(256) void linear2_kernel(
    const float* __restrict__ inA, const float* __restrict__ WA,
    const float* __restrict__ bA, float* __restrict__ outA,
    const float* __restrict__ inB, const float* __restrict__ WB,
    const float* __restrict__ bB, float* __restrict__ outB,
    int nchunks, int halfGrid)
{
    __shared__ ushort_t Wl[128 * 130];   // stride 130 -> 2-way bank aliasing (free)
    const bool isB = (int)blockIdx.x >= halfGrid;
    const float* in  = isB ? inB : inA;
    const float* W   = isB ? WB  : WA;
    const float* bv  = isB ? bB  : bA;
    float* out       = isB ? outB : outA;
    const int bid    = isB ? ((int)blockIdx.x - halfGrid) : (int)blockIdx.x;

    const int tid = threadIdx.x;
    for (int i = tid; i < 128 * 64; i += 256) {
        int row = i >> 6, cp = (i & 63) << 1;
        float2 w = *(const float2*)(W + row * 128 + cp);
        *(uint32_t*)(&Wl[row * 130 + cp]) = packbf(w.x, w.y);
    }
    const int j    = tid & 127;
    const int half = tid >> 7;
    const float bj = bv[j];
    __syncthreads();

    for (int c = bid; c < nchunks; c += halfGrid) {
        const int r0 = (c << 3) + (half << 2);   // 50000 = 8*6250 exact
        float acc0 = bj, acc1 = bj, acc2 = bj, acc3 = bj;
        const float* ip = in + (size_t)r0 * DD;
        #pragma unroll 4
        for (int d = 0; d < DD; d += 4) {
            uint32_t wpa = *(const uint32_t*)(&Wl[j * 130 + d]);
            uint32_t wpb = *(const uint32_t*)(&Wl[j * 130 + d + 2]);
            float w0 = bf2f(wpa & 0xffffu), w1 = bf2f(wpa >> 16);
            float w2 = bf2f(wpb & 0xffffu), w3 = bf2f(wpb >> 16);
            float4 x0 = *(const float4*)(ip + 0 * DD + d);
            float4 x1 = *(const float4*)(ip + 1 * DD + d);
            float4 x2 = *(const float4*)(ip + 2 * DD + d);
            float4 x3 = *(const float4*)(ip + 3 * DD + d);
            acc0 += x0.x * w0 + x0.y * w1 + x0.z * w2 + x0.w * w3;
            acc1 += x1.x * w0 + x1.y * w1 + x1.z * w2 + x1.w * w3;
            acc2 += x2.x * w0 + x2.y * w1 + x2.z * w2 + x2.w * w3;
            acc3 += x3.x * w0 + x3.y * w1 + x3.z * w2 + x3.w * w3;
        }
        out[(size_t)(r0 + 0) * DD + j] = acc0;
        out[(size_t)(r0 + 1) * DD + j] = acc1;
        out[(size_t)(r0 + 2) * DD + j] = acc2;
        out[(size_t)(r0 + 3) * DD + j] = acc3;
    }
}

// Fused attention + dual matvec + LN. LDS is only row buffers (8.3 KB);
// W1/W2 rows live in 64 VGPRs per thread (tid<128 -> W1 row j, else W2 row j).
// e_h ALIASES out (lives in d_out): e_h[n] read in phase A, out[n] written at the
// end of the same block-iteration; blocks own disjoint rows -> safe.
__global__ __launch_bounds__(256) void mega_kernel(
    const float* e_h, const float* __restrict__ e_t,
    const int* __restrict__ topk_idx, const float* __restrict__ topk_w,
    const float* __restrict__ x,
    const float* __restrict__ W1, const float* __restrict__ b1,
    const float* __restrict__ W2, const float* __restrict__ b2,
    const float* __restrict__ gamma, const float* __restrict__ beta,
    float* out, int niters)
{
    __shared__ float aL[4 * DD];
    __shared__ float mL[4 * DD];
    __shared__ float hA[4 * DD];
    __shared__ float hB[4 * DD];
    __shared__ float red[16];

    const int tid  = threadIdx.x;
    const int wv   = tid >> 6;    // wave 0..3 (phase A row)
    const int lane = tid & 63;
    const int half = tid >> 7;    // 0,1 (LN row pair)
    const int j    = tid & 127;   // column

    // W1 row j (tid<128) / W2 row j (tid>=128) -> 64 packed-bf16 registers
    uint32_t wreg[64];
    {
        const float* rp = ((tid < 128) ? W1 : W2) + (size_t)j * DD;
        #pragma unroll
        for (int i = 0; i < 32; ++i) {
            float4 w = ((const float4*)rp)[i];
            wreg[2 * i]     = packbf(w.x, w.y);
            wreg[2 * i + 1] = packbf(w.z, w.w);
        }
    }
    const float bsel = (tid < 128) ? b1[j] : b2[j];
    const float gj   = gamma[j], btj = beta[j];

    for (int c = blockIdx.x; c < niters; c += gridDim.x) {
        const int r0 = c << 2;
        // ---- phase A: wave wv -> row n = r0+wv; lane owns dims {2*lane, 2*lane+1} ----
        {
            const int n = r0 + wv;
            const float2 ehv = *(const float2*)(e_h + (size_t)n * DD + 2 * lane);
            // prefetch all 16 gathers (independent loads in flight)
            float2 nb[KNB];
            #pragma unroll
            for (int k = 0; k < KNB; ++k) {
                int t = topk_idx[n * KNB + k];
                t = ((unsigned)t < (unsigned)NROWS) ? t : 0;
                nb[k] = *(const float2*)(e_t + (size_t)t * DD + 2 * lane);
            }
            float s[KNB];
            #pragma unroll
            for (int k = 0; k < KNB; ++k) {
                const float p = topk_w[n * KNB + k];
                const float er0 = ehv.x + p * (nb[k].x - ehv.x);  // p*b+(1-p)*eh
                const float er1 = ehv.y + p * (nb[k].y - ehv.y);
                float part = nb[k].x * tanh_fast(ehv.x + er0)
                           + nb[k].y * tanh_fast(ehv.y + er1);
                #pragma unroll
                for (int off = 32; off >= 1; off >>= 1)
                    part += __shfl_xor(part, off, 64);
                s[k] = part;
            }
            float mx = s[0];
            #pragma unroll
            for (int k = 1; k < KNB; ++k) mx = fmaxf(mx, s[k]);
            float sum = 0.0f;
            #pragma unroll
            for (int k = 0; k < KNB; ++k) { s[k] = __expf(s[k] - mx); sum += s[k]; }
            const float inv = 1.0f / sum;
            float e0 = 0.0f, e1 = 0.0f;
            #pragma unroll
            for (int k = 0; k < KNB; ++k) { e0 += s[k] * nb[k].x; e1 += s[k] * nb[k].y; }
            e0 *= inv; e1 *= inv;

            const float2 xv = *(const float2*)(x + (size_t)n * DD + 2 * lane);
            *(float2*)(&aL[wv * DD + 2 * lane]) = make_float2(xv.x + e0, xv.y + e1);
            *(float2*)(&mL[wv * DD + 2 * lane]) = make_float2(xv.x * e0, xv.y * e1);
        }
        __syncthreads();   // aL/mL ready; all e_h reads for rows r0..r0+3 done

        // ---- phase B: thread = (matrix, column j); 4 rows from LDS (broadcast reads) ----
        {
            const float* vin = (tid < 128) ? aL : mL;
            float acc0 = bsel, acc1 = bsel, acc2 = bsel, acc3 = bsel;
            #pragma unroll
            for (int i = 0; i < 32; ++i) {
                const uint32_t wA = wreg[2 * i], wB = wreg[2 * i + 1];
                const float w0 = bf2f(wA & 0xffffu), w1 = bf2f(wA >> 16);
                const float w2 = bf2f(wB & 0xffffu), w3 = bf2f(wB >> 16);
                const float4 v0 = *(const float4*)(vin + 0 * DD + 4 * i);
                const float4 v1 = *(const float4*)(vin + 1 * DD + 4 * i);
                const float4 v2 = *(const float4*)(vin + 2 * DD + 4 * i);
                const float4 v3 = *(const float4*)(vin + 3 * DD + 4 * i);
                acc0 += v0.x * w0 + v0.y * w1 + v0.z * w2 + v0.w * w3;
                acc1 += v1.x * w0 + v1.y * w1 + v1.z * w2 + v1.w * w3;
                acc2 += v2.x * w0 + v2.y * w1 + v2.z * w2 + v2.w * w3;
                acc3 += v3.x * w0 + v3.y * w1 + v3.z * w2 + v3.w * w3;
            }
            float* hO = (tid < 128) ? hA : hB;
            hO[0 * DD + j] = leaky(acc0);
            hO[1 * DD + j] = leaky(acc1);
            hO[2 * DD + j] = leaky(acc2);
            hO[3 * DD + j] = leaky(acc3);
        }
        __syncthreads();

        // ---- LN: wave pair {2*half, 2*half+1} rows ----
        const int rA = 2 * half;
        float h0 = hA[rA * DD + j] + hB[rA * DD + j];
        float h1 = hA[(rA + 1) * DD + j] + hB[(rA + 1) * DD + j];
        float s0 = h0, q0 = h0 * h0, s1 = h1, q1 = h1 * h1;
        #pragma unroll
        for (int off = 32; off >= 1; off >>= 1) {
            s0 += __shfl_xor(s0, off, 64);
            q0 += __shfl_xor(q0, off, 64);
            s1 += __shfl_xor(s1, off, 64);
            q1 += __shfl_xor(q1, off, 64);
        }
        if (lane == 0) {
            red[wv * 4 + 0] = s0; red[wv * 4 + 1] = q0;
            red[wv * 4 + 2] = s1; red[wv * 4 + 3] = q1;
        }
        __syncthreads();
        const int base = (wv & 2);
        const float S0 = red[base * 4 + 0] + red[(base + 1) * 4 + 0];
        const float Q0 = red[base * 4 + 1] + red[(base + 1) * 4 + 1];
        const float S1 = red[base * 4 + 2] + red[(base + 1) * 4 + 2];
        const float Q1 = red[base * 4 + 3] + red[(base + 1) * 4 + 3];
        const float mu0  = S0 * (1.0f / DD);
        const float var0 = Q0 * (1.0f / DD) - mu0 * mu0;
        const float mu1  = S1 * (1.0f / DD);
        const float var1 = Q1 * (1.0f / DD) - mu1 * mu1;
        out[(size_t)(r0 + rA) * DD + j]     = (h0 - mu0) * rsqrtf(var0 + LN_EPS) * gj + btj;
        out[(size_t)(r0 + rA + 1) * DD + j] = (h1 - mu1) * rsqrtf(var1 + LN_EPS) * gj + btj;
        __syncthreads();   // protect aL/mL/hA/hB/red for next iteration
    }
}

extern "C" void kernel_launch(void* const* d_in, const int* in_sizes, int n_in,
                              void* d_out, int out_size, void* d_ws, size_t ws_size,
                              hipStream_t stream) {
    const float* x      = (const float*)d_in[0];
    const float* ehi    = (const float*)d_in[1];
    const float* eti    = (const float*)d_in[2];
    const int*   tidx   = (const int*)d_in[3];
    const float* tw     = (const float*)d_in[4];
    const float* Wh     = (const float*)d_in[5];
    const float* bh     = (const float*)d_in[6];
    const float* Wt     = (const float*)d_in[7];
    const float* bt     = (const float*)d_in[8];
    const float* W1     = (const float*)d_in[9];
    const float* b1     = (const float*)d_in[10];
    const float* W2     = (const float*)d_in[11];
    const float* b2     = (const float*)d_in[12];
    const float* gamma  = (const float*)d_in[13];
    const float* beta   = (const float*)d_in[14];

    float* e_h = (float*)d_out;   // e_h staged in fp32 output buffer (exact fit)
    float* e_t = (float*)d_ws;    // 25.6 MB of ws

    linear2_kernel<<<2048, 256, 0, stream>>>(ehi, Wh, bh, e_h,
                                             eti, Wt, bt, e_t,
                                             NROWS / 8, 1024);
    mega_kernel<<<1024, 256, 0, stream>>>(e_h, e_t, tidx, tw, x,
                                          W1, b1, W2, b2, gamma, beta,
                                          (float*)d_out, NROWS / 4);
}

// Round 9
// 537.258 us; speedup vs baseline: 1.7473x; 1.7473x over previous
//
#include <hip/hip_runtime.h>
#include <stdint.h>

#define NROWS 50000
#define KNB 16
#define DD 128
#define LN_EPS 1e-5f

typedef unsigned short ushort_t;

static __device__ __forceinline__ float bf2f(uint32_t u) {
    union { uint32_t i; float f; } v; v.i = u << 16; return v.f;
}
static __device__ __forceinline__ ushort_t f2bf(float f) {
    union { float f; uint32_t i; } v; v.f = f;
    uint32_t x = v.i;
    return (ushort_t)((x + 0x7fffu + ((x >> 16) & 1u)) >> 16);
}
static __device__ __forceinline__ uint32_t packbf(float a, float b) {
    return (uint32_t)f2bf(a) | ((uint32_t)f2bf(b) << 16);
}
static __device__ __forceinline__ float leaky(float v) {
    return v > 0.0f ? v : 0.01f * v;
}
// tanh(z) = 1 - 2/(e^{2z}+1); saturates correctly for large |z|
static __device__ __forceinline__ float tanh_fast(float z) {
    float e = __expf(2.0f * z);
    return 1.0f - 2.0f / (e + 1.0f);
}

// out[r][j] = sum_d in[r][d] * W[j][d] + bias[j]   (fp32 in/bias/out; W -> LDS bf16)
// R7-proven: 117 us per launch.
__global__ __launch_bounds__(128) void linear_kernel(
    const float* __restrict__ in, const float* __restrict__ W,
    const float* __restrict__ bias, float* __restrict__ out,
    int nchunks)
{
    __shared__ ushort_t Wl[128 * 130];   // stride 130: 2-way bank aliasing only (free)
    const int tid = threadIdx.x;
    for (int i = tid; i < 128 * 64; i += 128) {
        int row = i >> 6;
        int cp  = (i & 63) << 1;
        float2 w = *(const float2*)(W + row * 128 + cp);
        *(uint32_t*)(&Wl[row * 130 + cp]) = packbf(w.x, w.y);
    }
    const int j = tid;
    const float bj = bias[j];
    __syncthreads();

    for (int c = blockIdx.x; c < nchunks; c += gridDim.x) {
        const int r0 = c << 2;   // 50000 = 4*12500, no tail
        float acc0 = bj, acc1 = bj, acc2 = bj, acc3 = bj;
        const float* ip = in + (size_t)r0 * DD;
        #pragma unroll 4
        for (int d = 0; d < DD; d += 4) {
            uint32_t wpa = *(const uint32_t*)(&Wl[j * 130 + d]);
            uint32_t wpb = *(const uint32_t*)(&Wl[j * 130 + d + 2]);
            float w0 = bf2f(wpa & 0xffffu), w1 = bf2f(wpa >> 16);
            float w2 = bf2f(wpb & 0xffffu), w3 = bf2f(wpb >> 16);
            float4 x0 = *(const float4*)(ip + 0 * DD + d);
            float4 x1 = *(const float4*)(ip + 1 * DD + d);
            float4 x2 = *(const float4*)(ip + 2 * DD + d);
            float4 x3 = *(const float4*)(ip + 3 * DD + d);
            acc0 += x0.x * w0 + x0.y * w1 + x0.z * w2 + x0.w * w3;
            acc1 += x1.x * w0 + x1.y * w1 + x1.z * w2 + x1.w * w3;
            acc2 += x2.x * w0 + x2.y * w1 + x2.z * w2 + x2.w * w3;
            acc3 += x3.x * w0 + x3.y * w1 + x3.z * w2 + x3.w * w3;
        }
        out[(size_t)(r0 + 0) * DD + j] = acc0;
        out[(size_t)(r0 + 1) * DD + j] = acc1;
        out[(size_t)(r0 + 2) * DD + j] = acc2;
        out[(size_t)(r0 + 3) * DD + j] = acc3;
    }
}

// R7 mega with ONE change: phase A's idx->gather->compute serial chain is broken:
// scalar (wave-uniform) index/weight loads, then all 16 gathers batched in flight.
// e_h ALIASES out (lives in d_out): row n's e_h read in phase A, out[n] written in
// phase B of the same block-iteration, barrier-separated; disjoint rows per block.
__global__ __launch_bounds__(256) void mega_kernel(
    const float* e_h, const float* __restrict__ e_t,
    const int* __restrict__ topk_idx, const float* __restrict__ topk_w,
    const float* __restrict__ x,
    const float* __restrict__ W1, const float* __restrict__ b1,
    const float* __restrict__ W2, const float* __restrict__ b2,
    const float* __restrict__ gamma, const float* __restrict__ beta,
    float* out, int niters)
{
    __shared__ ushort_t W1l[128 * 130];
    __shared__ ushort_t W2l[128 * 130];
    __shared__ float aL[4 * 128];
    __shared__ float mL[4 * 128];
    __shared__ float red[16];

    const int tid  = threadIdx.x;
    const int wv   = tid >> 6;        // wave 0..3  (phase A: row wv)
    const int lane = tid & 63;
    const int half = tid >> 7;        // 0,1        (phase B: row pair)
    const int j    = tid & 127;       // column

    for (int i = tid; i < 128 * 64; i += 256) {
        int row = i >> 6;
        int cp  = (i & 63) << 1;
        float2 w1 = *(const float2*)(W1 + row * 128 + cp);
        float2 w2 = *(const float2*)(W2 + row * 128 + cp);
        *(uint32_t*)(&W1l[row * 130 + cp]) = packbf(w1.x, w1.y);
        *(uint32_t*)(&W2l[row * 130 + cp]) = packbf(w2.x, w2.y);
    }
    const float b1j = b1[j], b2j = b2[j];
    const float gj  = gamma[j], btj = beta[j];
    __syncthreads();

    for (int c = blockIdx.x; c < niters; c += gridDim.x) {
        const int r0 = c << 2;
        // ---- phase A: wave wv -> row n = r0+wv; lane owns dims {2*lane, 2*lane+1} ----
        {
            const int nu = __builtin_amdgcn_readfirstlane(r0 + wv);  // wave-uniform row
            // 1) scalar loads of the 16 indices + 16 weights (2x s_load_dwordx8 each)
            int   tk[KNB];
            float pk[KNB];
            #pragma unroll
            for (int k = 0; k < KNB; ++k) tk[k] = topk_idx[nu * KNB + k];
            #pragma unroll
            for (int k = 0; k < KNB; ++k) pk[k] = topk_w[nu * KNB + k];
            // 2) all 16 gathers issued back-to-back (independent, in flight together)
            float2 nb[KNB];
            #pragma unroll
            for (int k = 0; k < KNB; ++k) {
                int t = tk[k];
                t = ((unsigned)t < (unsigned)NROWS) ? t : 0;
                nb[k] = *(const float2*)(e_t + (size_t)t * DD + 2 * lane);
            }
            const float2 ehv = *(const float2*)(e_h + (size_t)nu * DD + 2 * lane);
            const float2 xv  = *(const float2*)(x   + (size_t)nu * DD + 2 * lane);

            // 3) compute (pure VALU + DS-swizzle, no memory in the chain)
            float s[KNB];
            #pragma unroll
            for (int k = 0; k < KNB; ++k) {
                const float p = pk[k];
                const float er0 = ehv.x + p * (nb[k].x - ehv.x);  // p*b + (1-p)*eh
                const float er1 = ehv.y + p * (nb[k].y - ehv.y);
                float part = nb[k].x * tanh_fast(ehv.x + er0)
                           + nb[k].y * tanh_fast(ehv.y + er1);
                #pragma unroll
                for (int off = 32; off >= 1; off >>= 1)
                    part += __shfl_xor(part, off, 64);
                s[k] = part;
            }
            float mx = s[0];
            #pragma unroll
            for (int k = 1; k < KNB; ++k) mx = fmaxf(mx, s[k]);
            float sum = 0.0f;
            #pragma unroll
            for (int k = 0; k < KNB; ++k) { s[k] = __expf(s[k] - mx); sum += s[k]; }
            const float inv = 1.0f / sum;
            float e0 = 0.0f, e1 = 0.0f;
            #pragma unroll
            for (int k = 0; k < KNB; ++k) { e0 += s[k] * nb[k].x; e1 += s[k] * nb[k].y; }
            e0 *= inv; e1 *= inv;

            aL[wv * DD + 2 * lane]     = xv.x + e0;
            aL[wv * DD + 2 * lane + 1] = xv.y + e1;
            mL[wv * DD + 2 * lane]     = xv.x * e0;
            mL[wv * DD + 2 * lane + 1] = xv.y * e1;
        }
        __syncthreads();   // aL/mL ready; all e_h reads for rows r0..r0+3 complete

        // ---- phase B (R7-proven): thread (half, j): rows r0+2*half(+1), column j ----
        float aA0 = b1j, aA1 = b1j, aB0 = b2j, aB1 = b2j;
        const float* pa = &aL[(2 * half) * DD];
        const float* pm = &mL[(2 * half) * DD];
        #pragma unroll 8
        for (int d = 0; d < DD; d += 2) {
            uint32_t w1p = *(const uint32_t*)(&W1l[j * 130 + d]);
            uint32_t w2p = *(const uint32_t*)(&W2l[j * 130 + d]);
            float w10 = bf2f(w1p & 0xffffu), w11 = bf2f(w1p >> 16);
            float w20 = bf2f(w2p & 0xffffu), w21 = bf2f(w2p >> 16);
            float a00 = pa[d],      a01 = pa[d + 1];
            float a10 = pa[DD + d], a11 = pa[DD + d + 1];
            float m00 = pm[d],      m01 = pm[d + 1];
            float m10 = pm[DD + d], m11 = pm[DD + d + 1];
            aA0 += a00 * w10 + a01 * w11;
            aA1 += a10 * w10 + a11 * w11;
            aB0 += m00 * w20 + m01 * w21;
            aB1 += m10 * w20 + m11 * w21;
        }
        float h0 = leaky(aA0) + leaky(aB0);   // row r0+2*half
        float h1 = leaky(aA1) + leaky(aB1);   // row r0+2*half+1

        float s0 = h0, q0 = h0 * h0, s1 = h1, q1 = h1 * h1;
        #pragma unroll
        for (int off = 32; off >= 1; off >>= 1) {
            s0 += __shfl_xor(s0, off, 64);
            q0 += __shfl_xor(q0, off, 64);
            s1 += __shfl_xor(s1, off, 64);
            q1 += __shfl_xor(q1, off, 64);
        }
        if (lane == 0) {
            red[wv * 4 + 0] = s0; red[wv * 4 + 1] = q0;
            red[wv * 4 + 2] = s1; red[wv * 4 + 3] = q1;
        }
        __syncthreads();
        const int base = (wv & 2);   // waves {0,1} -> 0, waves {2,3} -> 2
        const float S0 = red[base * 4 + 0] + red[(base + 1) * 4 + 0];
        const float Q0 = red[base * 4 + 1] + red[(base + 1) * 4 + 1];
        const float S1 = red[base * 4 + 2] + red[(base + 1) * 4 + 2];
        const float Q1 = red[base * 4 + 3] + red[(base + 1) * 4 + 3];
        const float mu0  = S0 * (1.0f / DD);
        const float var0 = Q0 * (1.0f / DD) - mu0 * mu0;
        const float mu1  = S1 * (1.0f / DD);
        const float var1 = Q1 * (1.0f / DD) - mu1 * mu1;
        const int rA = r0 + 2 * half;
        out[(size_t)rA * DD + j]       = (h0 - mu0) * rsqrtf(var0 + LN_EPS) * gj + btj;
        out[(size_t)(rA + 1) * DD + j] = (h1 - mu1) * rsqrtf(var1 + LN_EPS) * gj + btj;
        __syncthreads();   // protect aL/mL/red before next iteration
    }
}

extern "C" void kernel_launch(void* const* d_in, const int* in_sizes, int n_in,
                              void* d_out, int out_size, void* d_ws, size_t ws_size,
                              hipStream_t stream) {
    const float* x      = (const float*)d_in[0];
    const float* ehi    = (const float*)d_in[1];
    const float* eti    = (const float*)d_in[2];
    const int*   tidx   = (const int*)d_in[3];
    const float* tw     = (const float*)d_in[4];
    const float* Wh     = (const float*)d_in[5];
    const float* bh     = (const float*)d_in[6];
    const float* Wt     = (const float*)d_in[7];
    const float* bt     = (const float*)d_in[8];
    const float* W1     = (const float*)d_in[9];
    const float* b1     = (const float*)d_in[10];
    const float* W2     = (const float*)d_in[11];
    const float* b2     = (const float*)d_in[12];
    const float* gamma  = (const float*)d_in[13];
    const float* beta   = (const float*)d_in[14];

    float* e_h = (float*)d_out;   // e_h staged in fp32 output buffer (exact fit)
    float* e_t = (float*)d_ws;    // 25.6 MB of ws (proven)

    const int nchunks4 = NROWS / 4;   // 12500 exact

    linear_kernel<<<1024, 128, 0, stream>>>(ehi, Wh, bh, e_h, nchunks4);
    linear_kernel<<<1024, 128, 0, stream>>>(eti, Wt, bt, e_t, nchunks4);
    mega_kernel<<<1024, 256, 0, stream>>>(e_h, e_t, tidx, tw, x,
                                          W1, b1, W2, b2, gamma, beta,
                                          (float*)d_out, nchunks4);
}

// Round 10
// 417.923 us; speedup vs baseline: 2.2462x; 1.2855x over previous
//
#include <hip/hip_runtime.h>
#include <stdint.h>

#define NROWS 50000
#define KNB 16
#define DD 128
#define LN_EPS 1e-5f

typedef unsigned short ushort_t;
using frag_ab = __attribute__((ext_vector_type(8))) short;   // 8 bf16 (4 VGPRs)
using frag_cd = __attribute__((ext_vector_type(4))) float;   // 4 fp32 acc

static __device__ __forceinline__ float bf2f(uint32_t u) {
    union { uint32_t i; float f; } v; v.i = u << 16; return v.f;
}
static __device__ __forceinline__ ushort_t f2bf(float f) {
    union { float f; uint32_t i; } v; v.f = f;
    uint32_t x = v.i;
    return (ushort_t)((x + 0x7fffu + ((x >> 16) & 1u)) >> 16);
}
static __device__ __forceinline__ uint32_t packbf(float a, float b) {
    return (uint32_t)f2bf(a) | ((uint32_t)f2bf(b) << 16);
}
static __device__ __forceinline__ float leaky(float v) {
    return v > 0.0f ? v : 0.01f * v;
}
static __device__ __forceinline__ float tanh_fast(float z) {
    float e = __expf(2.0f * z);
    return 1.0f - 2.0f / (e + 1.0f);
}

// MFMA linear: out[r][j] = sum_d in[r][d]*W[j][d] + bias[j]
// Wave = 16 rows x 128 cols, K=128 in 4 chunks of 32. W in LDS (bf16, 272B rows).
// fp32 A enters as hi+lo bf16 split (two MFMAs) -> A-fidelity ~2^-17.
__global__ __launch_bounds__(256) void linear_mfma(
    const float* __restrict__ in, const float* __restrict__ W,
    const float* __restrict__ bias, float* __restrict__ out)
{
    __shared__ ushort_t Wl[128 * 136];   // row stride 136 shorts = 272 B (16B-aligned, 2-way banks = free)
    const int tid = threadIdx.x;
    for (int i = tid; i < 128 * 64; i += 256) {
        int row = i >> 6, cp = (i & 63) << 1;
        float2 w = *(const float2*)(W + row * 128 + cp);
        *(uint32_t*)(&Wl[row * 136 + cp]) = packbf(w.x, w.y);
    }
    const int wv = tid >> 6, lane = tid & 63;
    const int quad = lane >> 4, lq = lane & 15;
    float bn[8];
    #pragma unroll
    for (int nt = 0; nt < 8; ++nt) bn[nt] = bias[nt * 16 + lq];
    __syncthreads();

    const int r0 = blockIdx.x * 64 + wv * 16;     // wave's 16 rows
    const int arow = r0 + lq;                     // A-frag row for this lane (m = lane&15)
    const int arc = arow < NROWS ? arow : NROWS - 1;

    // A fragments: A[m=lq][k = c*32 + quad*8 + i], hi/lo split
    frag_ab Ahi[4], Alo[4];
    const float* ip = in + (size_t)arc * DD + quad * 8;
    #pragma unroll
    for (int c = 0; c < 4; ++c) {
        float4 u = *(const float4*)(ip + c * 32);
        float4 v = *(const float4*)(ip + c * 32 + 4);
        float uu[8] = {u.x, u.y, u.z, u.w, v.x, v.y, v.z, v.w};
        #pragma unroll
        for (int i = 0; i < 8; ++i) {
            ushort_t h = f2bf(uu[i]);
            float r = uu[i] - bf2f(h);
            Ahi[c][i] = (short)h;
            Alo[c][i] = (short)f2bf(r);
        }
    }

    #pragma unroll
    for (int nt = 0; nt < 8; ++nt) {
        frag_cd acc = {0.f, 0.f, 0.f, 0.f};
        #pragma unroll
        for (int c = 0; c < 4; ++c) {
            // B[k = c*32+quad*8+i][n = lq] = W[nt*16+lq][c*32+quad*8+i]
            frag_ab B = *(const frag_ab*)(&Wl[(nt * 16 + lq) * 136 + c * 32 + quad * 8]);
            acc = __builtin_amdgcn_mfma_f32_16x16x32_bf16(Alo[c], B, acc, 0, 0, 0);
            acc = __builtin_amdgcn_mfma_f32_16x16x32_bf16(Ahi[c], B, acc, 0, 0, 0);
        }
        // D[m = quad*4 + r][n = lq]
        #pragma unroll
        for (int r = 0; r < 4; ++r) {
            int orow = r0 + quad * 4 + r;
            if (orow < NROWS)
                out[(size_t)orow * DD + nt * 16 + lq] = acc[r] + bn[nt];
        }
    }
}

// R9-proven mega (byte-identical): scalar idx/weight loads, batched gathers,
// LDS W1/W2 phase B, LN epilogue. e_h ALIASES out (barrier-separated, disjoint rows).
__global__ __launch_bounds__(256) void mega_kernel(
    const float* e_h, const float* __restrict__ e_t,
    const int* __restrict__ topk_idx, const float* __restrict__ topk_w,
    const float* __restrict__ x,
    const float* __restrict__ W1, const float* __restrict__ b1,
    const float* __restrict__ W2, const float* __restrict__ b2,
    const float* __restrict__ gamma, const float* __restrict__ beta,
    float* out, int niters)
{
    __shared__ ushort_t W1l[128 * 130];
    __shared__ ushort_t W2l[128 * 130];
    __shared__ float aL[4 * 128];
    __shared__ float mL[4 * 128];
    __shared__ float red[16];

    const int tid  = threadIdx.x;
    const int wv   = tid >> 6;
    const int lane = tid & 63;
    const int half = tid >> 7;
    const int j    = tid & 127;

    for (int i = tid; i < 128 * 64; i += 256) {
        int row = i >> 6;
        int cp  = (i & 63) << 1;
        float2 w1 = *(const float2*)(W1 + row * 128 + cp);
        float2 w2 = *(const float2*)(W2 + row * 128 + cp);
        *(uint32_t*)(&W1l[row * 130 + cp]) = packbf(w1.x, w1.y);
        *(uint32_t*)(&W2l[row * 130 + cp]) = packbf(w2.x, w2.y);
    }
    const float b1j = b1[j], b2j = b2[j];
    const float gj  = gamma[j], btj = beta[j];
    __syncthreads();

    for (int c = blockIdx.x; c < niters; c += gridDim.x) {
        const int r0 = c << 2;
        {
            const int nu = __builtin_amdgcn_readfirstlane(r0 + wv);
            int   tk[KNB];
            float pk[KNB];
            #pragma unroll
            for (int k = 0; k < KNB; ++k) tk[k] = topk_idx[nu * KNB + k];
            #pragma unroll
            for (int k = 0; k < KNB; ++k) pk[k] = topk_w[nu * KNB + k];
            float2 nb[KNB];
            #pragma unroll
            for (int k = 0; k < KNB; ++k) {
                int t = tk[k];
                t = ((unsigned)t < (unsigned)NROWS) ? t : 0;
                nb[k] = *(const float2*)(e_t + (size_t)t * DD + 2 * lane);
            }
            const float2 ehv = *(const float2*)(e_h + (size_t)nu * DD + 2 * lane);
            const float2 xv  = *(const float2*)(x   + (size_t)nu * DD + 2 * lane);

            float s[KNB];
            #pragma unroll
            for (int k = 0; k < KNB; ++k) {
                const float p = pk[k];
                const float er0 = ehv.x + p * (nb[k].x - ehv.x);
                const float er1 = ehv.y + p * (nb[k].y - ehv.y);
                float part = nb[k].x * tanh_fast(ehv.x + er0)
                           + nb[k].y * tanh_fast(ehv.y + er1);
                #pragma unroll
                for (int off = 32; off >= 1; off >>= 1)
                    part += __shfl_xor(part, off, 64);
                s[k] = part;
            }
            float mx = s[0];
            #pragma unroll
            for (int k = 1; k < KNB; ++k) mx = fmaxf(mx, s[k]);
            float sum = 0.0f;
            #pragma unroll
            for (int k = 0; k < KNB; ++k) { s[k] = __expf(s[k] - mx); sum += s[k]; }
            const float inv = 1.0f / sum;
            float e0 = 0.0f, e1 = 0.0f;
            #pragma unroll
            for (int k = 0; k < KNB; ++k) { e0 += s[k] * nb[k].x; e1 += s[k] * nb[k].y; }
            e0 *= inv; e1 *= inv;

            aL[wv * DD + 2 * lane]     = xv.x + e0;
            aL[wv * DD + 2 * lane + 1] = xv.y + e1;
            mL[wv * DD + 2 * lane]     = xv.x * e0;
            mL[wv * DD + 2 * lane + 1] = xv.y * e1;
        }
        __syncthreads();

        float aA0 = b1j, aA1 = b1j, aB0 = b2j, aB1 = b2j;
        const float* pa = &aL[(2 * half) * DD];
        const float* pm = &mL[(2 * half) * DD];
        #pragma unroll 8
        for (int d = 0; d < DD; d += 2) {
            uint32_t w1p = *(const uint32_t*)(&W1l[j * 130 + d]);
            uint32_t w2p = *(const uint32_t*)(&W2l[j * 130 + d]);
            float w10 = bf2f(w1p & 0xffffu), w11 = bf2f(w1p >> 16);
            float w20 = bf2f(w2p & 0xffffu), w21 = bf2f(w2p >> 16);
            float a00 = pa[d],      a01 = pa[d + 1];
            float a10 = pa[DD + d], a11 = pa[DD + d + 1];
            float m00 = pm[d],      m01 = pm[d + 1];
            float m10 = pm[DD + d], m11 = pm[DD + d + 1];
            aA0 += a00 * w10 + a01 * w11;
            aA1 += a10 * w10 + a11 * w11;
            aB0 += m00 * w20 + m01 * w21;
            aB1 += m10 * w20 + m11 * w21;
        }
        float h0 = leaky(aA0) + leaky(aB0);
        float h1 = leaky(aA1) + leaky(aB1);

        float s0 = h0, q0 = h0 * h0, s1 = h1, q1 = h1 * h1;
        #pragma unroll
        for (int off = 32; off >= 1; off >>= 1) {
            s0 += __shfl_xor(s0, off, 64);
            q0 += __shfl_xor(q0, off, 64);
            s1 += __shfl_xor(s1, off, 64);
            q1 += __shfl_xor(q1, off, 64);
        }
        if (lane == 0) {
            red[wv * 4 + 0] = s0; red[wv * 4 + 1] = q0;
            red[wv * 4 + 2] = s1; red[wv * 4 + 3] = q1;
        }
        __syncthreads();
        const int base = (wv & 2);
        const float S0 = red[base * 4 + 0] + red[(base + 1) * 4 + 0];
        const float Q0 = red[base * 4 + 1] + red[(base + 1) * 4 + 1];
        const float S1 = red[base * 4 + 2] + red[(base + 1) * 4 + 2];
        const float Q1 = red[base * 4 + 3] + red[(base + 1) * 4 + 3];
        const float mu0  = S0 * (1.0f / DD);
        const float var0 = Q0 * (1.0f / DD) - mu0 * mu0;
        const float mu1  = S1 * (1.0f / DD);
        const float var1 = Q1 * (1.0f / DD) - mu1 * mu1;
        const int rA = r0 + 2 * half;
        out[(size_t)rA * DD + j]       = (h0 - mu0) * rsqrtf(var0 + LN_EPS) * gj + btj;
        out[(size_t)(rA + 1) * DD + j] = (h1 - mu1) * rsqrtf(var1 + LN_EPS) * gj + btj;
        __syncthreads();
    }
}

extern "C" void kernel_launch(void* const* d_in, const int* in_sizes, int n_in,
                              void* d_out, int out_size, void* d_ws, size_t ws_size,
                              hipStream_t stream) {
    const float* x      = (const float*)d_in[0];
    const float* ehi    = (const float*)d_in[1];
    const float* eti    = (const float*)d_in[2];
    const int*   tidx   = (const int*)d_in[3];
    const float* tw     = (const float*)d_in[4];
    const float* Wh     = (const float*)d_in[5];
    const float* bh     = (const float*)d_in[6];
    const float* Wt     = (const float*)d_in[7];
    const float* bt     = (const float*)d_in[8];
    const float* W1     = (const float*)d_in[9];
    const float* b1     = (const float*)d_in[10];
    const float* W2     = (const float*)d_in[11];
    const float* b2     = (const float*)d_in[12];
    const float* gamma  = (const float*)d_in[13];
    const float* beta   = (const float*)d_in[14];

    float* e_h = (float*)d_out;   // e_h staged in fp32 output buffer (exact fit)
    float* e_t = (float*)d_ws;    // 25.6 MB of ws (proven)

    const int nblk = (NROWS + 63) / 64;   // 782

    linear_mfma<<<nblk, 256, 0, stream>>>(ehi, Wh, bh, e_h);
    linear_mfma<<<nblk, 256, 0, stream>>>(eti, Wt, bt, e_t);
    mega_kernel<<<1024, 256, 0, stream>>>(e_h, e_t, tidx, tw, x,
                                          W1, b1, W2, b2, gamma, beta,
                                          (float*)d_out, NROWS / 4);
}

// Round 11
// 310.740 us; speedup vs baseline: 3.0209x; 1.3449x over previous
//
#include <hip/hip_runtime.h>
#include <stdint.h>

#define NROWS 50000
#define KNB 16
#define DD 128
#define LN_EPS 1e-5f

typedef unsigned short ushort_t;
using frag_ab = __attribute__((ext_vector_type(8))) short;   // 8 bf16 (4 VGPRs)
using frag_cd = __attribute__((ext_vector_type(4))) float;   // 4 fp32 acc

static __device__ __forceinline__ float bf2f(uint32_t u) {
    union { uint32_t i; float f; } v; v.i = u << 16; return v.f;
}
static __device__ __forceinline__ ushort_t f2bf(float f) {
    union { float f; uint32_t i; } v; v.f = f;
    uint32_t x = v.i;
    return (ushort_t)((x + 0x7fffu + ((x >> 16) & 1u)) >> 16);
}
static __device__ __forceinline__ uint32_t packbf(float a, float b) {
    return (uint32_t)f2bf(a) | ((uint32_t)f2bf(b) << 16);
}
static __device__ __forceinline__ float leaky(float v) {
    return v > 0.0f ? v : 0.01f * v;
}
static __device__ __forceinline__ float tanh_fast(float z) {
    float e = __expf(2.0f * z);
    return 1.0f - 2.0f / (e + 1.0f);
}
// split fp32 -> (hi, lo) bf16 pair
static __device__ __forceinline__ void split_bf(float f, ushort_t& hi, ushort_t& lo) {
    hi = f2bf(f);
    lo = f2bf(f - bf2f(hi));
}

// R10-proven MFMA linear: out[r][j] = sum_d in[r][d]*W[j][d] + bias[j]
__global__ __launch_bounds__(256) void linear_mfma(
    const float* __restrict__ in, const float* __restrict__ W,
    const float* __restrict__ bias, float* __restrict__ out)
{
    __shared__ ushort_t Wl[128 * 136];
    const int tid = threadIdx.x;
    for (int i = tid; i < 128 * 64; i += 256) {
        int row = i >> 6, cp = (i & 63) << 1;
        float2 w = *(const float2*)(W + row * 128 + cp);
        *(uint32_t*)(&Wl[row * 136 + cp]) = packbf(w.x, w.y);
    }
    const int wv = tid >> 6, lane = tid & 63;
    const int quad = lane >> 4, lq = lane & 15;
    float bn[8];
    #pragma unroll
    for (int nt = 0; nt < 8; ++nt) bn[nt] = bias[nt * 16 + lq];
    __syncthreads();

    const int r0 = blockIdx.x * 64 + wv * 16;
    const int arow = r0 + lq;
    const int arc = arow < NROWS ? arow : NROWS - 1;

    frag_ab Ahi[4], Alo[4];
    const float* ip = in + (size_t)arc * DD + quad * 8;
    #pragma unroll
    for (int c = 0; c < 4; ++c) {
        float4 u = *(const float4*)(ip + c * 32);
        float4 v = *(const float4*)(ip + c * 32 + 4);
        float uu[8] = {u.x, u.y, u.z, u.w, v.x, v.y, v.z, v.w};
        #pragma unroll
        for (int i = 0; i < 8; ++i) {
            ushort_t h, l; split_bf(uu[i], h, l);
            Ahi[c][i] = (short)h; Alo[c][i] = (short)l;
        }
    }

    #pragma unroll
    for (int nt = 0; nt < 8; ++nt) {
        frag_cd acc = {0.f, 0.f, 0.f, 0.f};
        #pragma unroll
        for (int c = 0; c < 4; ++c) {
            frag_ab B = *(const frag_ab*)(&Wl[(nt * 16 + lq) * 136 + c * 32 + quad * 8]);
            acc = __builtin_amdgcn_mfma_f32_16x16x32_bf16(Alo[c], B, acc, 0, 0, 0);
            acc = __builtin_amdgcn_mfma_f32_16x16x32_bf16(Ahi[c], B, acc, 0, 0, 0);
        }
        #pragma unroll
        for (int r = 0; r < 4; ++r) {
            int orow = r0 + quad * 4 + r;
            if (orow < NROWS)
                out[(size_t)orow * DD + nt * 16 + lq] = acc[r] + bn[nt];
        }
    }
}

// Mega v3: 16 rows/iteration. Phase A = R9 attention (x4 per wave) -> a,m as
// hi/lo bf16 in LDS. Phase B = MFMA dual matvec, W1/W2 B-frags in registers.
// LN from hL. e_h ALIASES out: rows read in phase A, written in LN of the same
// iteration, barrier-separated; blocks own disjoint rows.
__global__ __launch_bounds__(256, 3) void mega_kernel(
    const float* e_h, const float* __restrict__ e_t,
    const int* __restrict__ topk_idx, const float* __restrict__ topk_w,
    const float* __restrict__ x,
    const float* __restrict__ W1, const float* __restrict__ b1,
    const float* __restrict__ W2, const float* __restrict__ b2,
    const float* __restrict__ gamma, const float* __restrict__ beta,
    float* out, int niters)
{
    __shared__ ushort_t aHi[16][136], aLo[16][136];   // row stride 272B (16B-aligned)
    __shared__ ushort_t mHi[16][136], mLo[16][136];
    __shared__ float hL[16][132];

    const int tid  = threadIdx.x;
    const int wv   = tid >> 6;
    const int lane = tid & 63;
    const int quad = lane >> 4, lq = lane & 15;
    const int n0   = wv * 32;   // this wave's 32 output columns

    // B-frags for W1/W2 (hi-only bf16), held in registers for the whole kernel:
    // B[k=quad*8+i][n=lq] = W[n0+t*16+lq][c*32+quad*8+i]
    frag_ab BW1[2][4], BW2[2][4];
    #pragma unroll
    for (int t = 0; t < 2; ++t) {
        const float* r1 = W1 + (size_t)(n0 + t * 16 + lq) * DD + quad * 8;
        const float* r2 = W2 + (size_t)(n0 + t * 16 + lq) * DD + quad * 8;
        #pragma unroll
        for (int c = 0; c < 4; ++c) {
            float4 u = *(const float4*)(r1 + c * 32);
            float4 v = *(const float4*)(r1 + c * 32 + 4);
            float uu[8] = {u.x, u.y, u.z, u.w, v.x, v.y, v.z, v.w};
            #pragma unroll
            for (int i = 0; i < 8; ++i) BW1[t][c][i] = (short)f2bf(uu[i]);
            float4 p = *(const float4*)(r2 + c * 32);
            float4 q = *(const float4*)(r2 + c * 32 + 4);
            float vv[8] = {p.x, p.y, p.z, p.w, q.x, q.y, q.z, q.w};
            #pragma unroll
            for (int i = 0; i < 8; ++i) BW2[t][c][i] = (short)f2bf(vv[i]);
        }
    }
    float b1v[2], b2v[2];
    #pragma unroll
    for (int t = 0; t < 2; ++t) {
        b1v[t] = b1[n0 + t * 16 + lq];
        b2v[t] = b2[n0 + t * 16 + lq];
    }
    const float g0 = gamma[lane], g1 = gamma[lane + 64];
    const float be0 = beta[lane], be1 = beta[lane + 64];

    for (int c = blockIdx.x; c < niters; c += gridDim.x) {
        const int r0 = c << 4;   // 16 rows per iteration (50000 = 16*3125)

        // ---- phase A: wave wv -> rows r0+4*wv+q; lane owns dims {2*lane, 2*lane+1} ----
        #pragma unroll
        for (int q = 0; q < 4; ++q) {
            const int lr = 4 * wv + q;
            const int nu = __builtin_amdgcn_readfirstlane(r0 + lr);
            int   tk[KNB];
            float pk[KNB];
            #pragma unroll
            for (int k = 0; k < KNB; ++k) tk[k] = topk_idx[nu * KNB + k];
            #pragma unroll
            for (int k = 0; k < KNB; ++k) pk[k] = topk_w[nu * KNB + k];
            float2 nb[KNB];
            #pragma unroll
            for (int k = 0; k < KNB; ++k) {
                int t = tk[k];
                t = ((unsigned)t < (unsigned)NROWS) ? t : 0;
                nb[k] = *(const float2*)(e_t + (size_t)t * DD + 2 * lane);
            }
            const float2 ehv = *(const float2*)(e_h + (size_t)nu * DD + 2 * lane);
            const float2 xv  = *(const float2*)(x   + (size_t)nu * DD + 2 * lane);

            float s[KNB];
            #pragma unroll
            for (int k = 0; k < KNB; ++k) {
                const float p = pk[k];
                const float er0 = ehv.x + p * (nb[k].x - ehv.x);
                const float er1 = ehv.y + p * (nb[k].y - ehv.y);
                float part = nb[k].x * tanh_fast(ehv.x + er0)
                           + nb[k].y * tanh_fast(ehv.y + er1);
                #pragma unroll
                for (int off = 32; off >= 1; off >>= 1)
                    part += __shfl_xor(part, off, 64);
                s[k] = part;
            }
            float mx = s[0];
            #pragma unroll
            for (int k = 1; k < KNB; ++k) mx = fmaxf(mx, s[k]);
            float sum = 0.0f;
            #pragma unroll
            for (int k = 0; k < KNB; ++k) { s[k] = __expf(s[k] - mx); sum += s[k]; }
            const float inv = 1.0f / sum;
            float e0 = 0.0f, e1 = 0.0f;
            #pragma unroll
            for (int k = 0; k < KNB; ++k) { e0 += s[k] * nb[k].x; e1 += s[k] * nb[k].y; }
            e0 *= inv; e1 *= inv;

            const float a0 = xv.x + e0, a1 = xv.y + e1;
            const float m0 = xv.x * e0, m1 = xv.y * e1;
            ushort_t h0, l0, h1, l1;
            split_bf(a0, h0, l0); split_bf(a1, h1, l1);
            *(uint32_t*)(&aHi[lr][2 * lane]) = (uint32_t)h0 | ((uint32_t)h1 << 16);
            *(uint32_t*)(&aLo[lr][2 * lane]) = (uint32_t)l0 | ((uint32_t)l1 << 16);
            split_bf(m0, h0, l0); split_bf(m1, h1, l1);
            *(uint32_t*)(&mHi[lr][2 * lane]) = (uint32_t)h0 | ((uint32_t)h1 << 16);
            *(uint32_t*)(&mLo[lr][2 * lane]) = (uint32_t)l0 | ((uint32_t)l1 << 16);
        }
        __syncthreads();   // a/m staged for all 16 rows; e_h reads complete

        // ---- phase B: MFMA. A[m=lq][k], B in regs, D[m=quad*4+r][n=lq] ----
        {
            frag_cd aA0 = {0.f,0.f,0.f,0.f}, aA1 = {0.f,0.f,0.f,0.f};
            frag_cd aM0 = {0.f,0.f,0.f,0.f}, aM1 = {0.f,0.f,0.f,0.f};
            #pragma unroll
            for (int kc = 0; kc < 4; ++kc) {
                frag_ab Ah = *(const frag_ab*)(&aHi[lq][kc * 32 + quad * 8]);
                frag_ab Al = *(const frag_ab*)(&aLo[lq][kc * 32 + quad * 8]);
                frag_ab Mh = *(const frag_ab*)(&mHi[lq][kc * 32 + quad * 8]);
                frag_ab Ml = *(const frag_ab*)(&mLo[lq][kc * 32 + quad * 8]);
                aA0 = __builtin_amdgcn_mfma_f32_16x16x32_bf16(Al, BW1[0][kc], aA0, 0, 0, 0);
                aA0 = __builtin_amdgcn_mfma_f32_16x16x32_bf16(Ah, BW1[0][kc], aA0, 0, 0, 0);
                aA1 = __builtin_amdgcn_mfma_f32_16x16x32_bf16(Al, BW1[1][kc], aA1, 0, 0, 0);
                aA1 = __builtin_amdgcn_mfma_f32_16x16x32_bf16(Ah, BW1[1][kc], aA1, 0, 0, 0);
                aM0 = __builtin_amdgcn_mfma_f32_16x16x32_bf16(Ml, BW2[0][kc], aM0, 0, 0, 0);
                aM0 = __builtin_amdgcn_mfma_f32_16x16x32_bf16(Mh, BW2[0][kc], aM0, 0, 0, 0);
                aM1 = __builtin_amdgcn_mfma_f32_16x16x32_bf16(Ml, BW2[1][kc], aM1, 0, 0, 0);
                aM1 = __builtin_amdgcn_mfma_f32_16x16x32_bf16(Mh, BW2[1][kc], aM1, 0, 0, 0);
            }
            #pragma unroll
            for (int r = 0; r < 4; ++r) {
                const int row = quad * 4 + r;
                hL[row][n0 + lq]      = leaky(aA0[r] + b1v[0]) + leaky(aM0[r] + b2v[0]);
                hL[row][n0 + 16 + lq] = leaky(aA1[r] + b1v[1]) + leaky(aM1[r] + b2v[1]);
            }
        }
        __syncthreads();

        // ---- LN: wave wv -> rows 4*wv..4*wv+3; lane owns cols {lane, lane+64} ----
        #pragma unroll
        for (int q = 0; q < 4; ++q) {
            const int lr = 4 * wv + q;
            const float h0 = hL[lr][lane], h1 = hL[lr][lane + 64];
            float s = h0 + h1, qq = h0 * h0 + h1 * h1;
            #pragma unroll
            for (int off = 32; off >= 1; off >>= 1) {
                s  += __shfl_xor(s,  off, 64);
                qq += __shfl_xor(qq, off, 64);
            }
            const float mu  = s * (1.0f / DD);
            const float var = qq * (1.0f / DD) - mu * mu;
            const float rs  = rsqrtf(var + LN_EPS);
            out[(size_t)(r0 + lr) * DD + lane]      = (h0 - mu) * rs * g0 + be0;
            out[(size_t)(r0 + lr) * DD + lane + 64] = (h1 - mu) * rs * g1 + be1;
        }
        __syncthreads();   // protect LDS buffers before next iteration
    }
}

extern "C" void kernel_launch(void* const* d_in, const int* in_sizes, int n_in,
                              void* d_out, int out_size, void* d_ws, size_t ws_size,
                              hipStream_t stream) {
    const float* x      = (const float*)d_in[0];
    const float* ehi    = (const float*)d_in[1];
    const float* eti    = (const float*)d_in[2];
    const int*   tidx   = (const int*)d_in[3];
    const float* tw     = (const float*)d_in[4];
    const float* Wh     = (const float*)d_in[5];
    const float* bh     = (const float*)d_in[6];
    const float* Wt     = (const float*)d_in[7];
    const float* bt     = (const float*)d_in[8];
    const float* W1     = (const float*)d_in[9];
    const float* b1     = (const float*)d_in[10];
    const float* W2     = (const float*)d_in[11];
    const float* b2     = (const float*)d_in[12];
    const float* gamma  = (const float*)d_in[13];
    const float* beta   = (const float*)d_in[14];

    float* e_h = (float*)d_out;   // staged in fp32 output buffer (exact fit)
    float* e_t = (float*)d_ws;    // 25.6 MB of ws (proven)

    const int nblk = (NROWS + 63) / 64;   // 782

    linear_mfma<<<nblk, 256, 0, stream>>>(ehi, Wh, bh, e_h);
    linear_mfma<<<nblk, 256, 0, stream>>>(eti, Wt, bt, e_t);
    mega_kernel<<<625, 256, 0, stream>>>(e_h, e_t, tidx, tw, x,
                                         W1, b1, W2, b2, gamma, beta,
                                         (float*)d_out, NROWS / 16);
}